// Round 1
// baseline (621.920 us; speedup 1.0000x reference)
//
#include <hip/hip_runtime.h>
#include <hip/hip_bf16.h>

// Problem: sparse bottleneck block, B=32, Cin=Cout=256, width=64, H=W=56.
// All tensors f32 (per reference). Round 1: correct, reasonably-tiled f32.
// ws layout: h1 [32][64][3136] | h2 [32][64][3136] | mask [32][3136]

#define BATCH 32
#define CIN   256
#define WIDTH 64
#define COUT  256
#define HH    56
#define WW    56
#define HW    3136          // 56*56
#define PXT   64            // pixels per tile for 1x1-conv GEMMs (3136 = 49*64)
#define EPS   1e-5f

// ---------------------------------------------------------------------------
// k1: h1 = relu(bn1(conv1(x)))   (mask_dilate applied later, in k2)
//     mask[b][p] = (dot(x[b,:,p], mask_w) + mask_b >= 0)
// GEMM per image: C[64 x 64px] = W1[64 x 256] * X[256 x 64px]
// ---------------------------------------------------------------------------
__global__ __launch_bounds__(256) void k1_conv1(
    const float* __restrict__ x, const float* __restrict__ w1,
    const float* __restrict__ g1, const float* __restrict__ b1,
    const float* __restrict__ m1, const float* __restrict__ v1,
    const float* __restrict__ mw, const float* __restrict__ mb,
    float* __restrict__ h1, float* __restrict__ mask)
{
    __shared__ float As[32][65];
    __shared__ float Bs[32][65];
    __shared__ float mws[32];

    const int tid  = threadIdx.x;
    const int bimg = blockIdx.y;
    const int p0   = blockIdx.x * PXT;
    const float* xb = x + (size_t)bimg * CIN * HW;
    const int tx = tid & 15, ty = tid >> 4;

    float acc[4][4] = {};
    float softacc = 0.f;

    for (int k0 = 0; k0 < CIN; k0 += 32) {
        #pragma unroll
        for (int e = 0; e < 8; ++e) {              // A tile: w1[m][k0+kk] -> As[kk][m]
            int li = tid + 256 * e;                // 0..2047
            int m  = li >> 5;
            int kk = li & 31;
            As[kk][m] = w1[m * CIN + k0 + kk];
        }
        #pragma unroll
        for (int e = 0; e < 8; ++e) {              // B tile: x[k][p0+j] -> Bs[kk][j]
            int li = tid + 256 * e;
            int kk = li >> 6;
            int j  = li & 63;
            Bs[kk][j] = xb[(size_t)(k0 + kk) * HW + p0 + j];
        }
        if (tid < 32) mws[tid] = mw[k0 + tid];
        __syncthreads();

        #pragma unroll
        for (int kk = 0; kk < 32; ++kk) {
            float a[4], b[4];
            #pragma unroll
            for (int i = 0; i < 4; ++i) a[i] = As[kk][ty * 4 + i];
            #pragma unroll
            for (int j = 0; j < 4; ++j) b[j] = Bs[kk][tx * 4 + j];
            #pragma unroll
            for (int i = 0; i < 4; ++i)
                #pragma unroll
                for (int j = 0; j < 4; ++j)
                    acc[i][j] += a[i] * b[j];
        }
        if (tid < 64) {                            // mask-conv partial (pixel = tid)
            float s = 0.f;
            #pragma unroll
            for (int kk = 0; kk < 32; ++kk) s += Bs[kk][tid] * mws[kk];
            softacc += s;
        }
        __syncthreads();
    }

    #pragma unroll
    for (int i = 0; i < 4; ++i) {
        int m = ty * 4 + i;
        float sc = g1[m] * rsqrtf(v1[m] + EPS);
        float sh = b1[m] - m1[m] * sc;
        #pragma unroll
        for (int j = 0; j < 4; ++j) {
            float hv = fmaxf(acc[i][j] * sc + sh, 0.f);
            h1[((size_t)bimg * WIDTH + m) * HW + p0 + tx * 4 + j] = hv;
        }
    }
    if (tid < 64) {
        float soft = softacc + mb[0];
        mask[bimg * HW + p0 + tid] = (soft >= 0.f) ? 1.f : 0.f;
    }
}

// ---------------------------------------------------------------------------
// k2: h2 = relu(bn2(conv2(h1 * mask_dilate))) * mask
// 8x8 output tile per block, all 64 out channels; mask_dilate computed from
// a 12x12 mask halo in LDS (exact: dilate = 3x3 max of {0,1} mask).
// ---------------------------------------------------------------------------
__global__ __launch_bounds__(256) void k2_conv2(
    const float* __restrict__ h1, const float* __restrict__ w2,
    const float* __restrict__ g2, const float* __restrict__ b2,
    const float* __restrict__ m2, const float* __restrict__ v2,
    const float* __restrict__ mask, float* __restrict__ h2)
{
    __shared__ float hs[16][10][10];
    __shared__ float ws2[64][144];
    __shared__ float msk[12][12];
    __shared__ float mdil[10][10];

    const int tid  = threadIdx.x;
    const int bimg = blockIdx.z;
    const int ty0  = blockIdx.y * 8;
    const int tx0  = blockIdx.x * 8;

    for (int i = tid; i < 144; i += 256) {
        int r = i / 12, c = i % 12;
        int yy = ty0 - 2 + r, xx = tx0 - 2 + c;
        float mv = (yy >= 0 && yy < HH && xx >= 0 && xx < WW)
                     ? mask[bimg * HW + yy * WW + xx] : 0.f;
        msk[r][c] = mv;
    }
    __syncthreads();
    for (int i = tid; i < 100; i += 256) {
        int r = i / 10, c = i % 10;
        float mx = 0.f;
        #pragma unroll
        for (int dy = 0; dy < 3; ++dy)
            #pragma unroll
            for (int dx = 0; dx < 3; ++dx)
                mx = fmaxf(mx, msk[r + dy][c + dx]);
        mdil[r][c] = mx;                 // dilated mask at pixel (ty0-1+r, tx0-1+c)
    }
    __syncthreads();

    const int px  = tid & 63;            // pixel 0..63 within 8x8 tile
    const int og  = tid >> 6;            // out-channel group 0..3 (wave-uniform)
    const int py  = px >> 3, pxx = px & 7;

    float acc[16] = {};

    for (int c0 = 0; c0 < WIDTH; c0 += 16) {
        for (int i = tid; i < 64 * 144; i += 256) {
            int o = i / 144, rest = i % 144;
            int cc = rest / 9, k = rest % 9;
            ws2[o][cc * 9 + k] = w2[((size_t)o * WIDTH + c0 + cc) * 9 + k];
        }
        for (int i = tid; i < 1600; i += 256) {
            int cc = i / 100, r = (i % 100) / 10, c = i % 10;
            int yy = ty0 - 1 + r, xx = tx0 - 1 + c;
            float v = 0.f;
            if (yy >= 0 && yy < HH && xx >= 0 && xx < WW)
                v = h1[((size_t)bimg * WIDTH + c0 + cc) * HW + yy * WW + xx]
                    * mdil[r][c];
            hs[cc][r][c] = v;
        }
        __syncthreads();

        for (int cc = 0; cc < 16; ++cc) {
            #pragma unroll
            for (int dy = 0; dy < 3; ++dy)
                #pragma unroll
                for (int dx = 0; dx < 3; ++dx) {
                    float v = hs[cc][py + dy][pxx + dx];
                    int k = dy * 3 + dx;
                    #pragma unroll
                    for (int oo = 0; oo < 16; ++oo)
                        acc[oo] += v * ws2[og * 16 + oo][cc * 9 + k];
                }
        }
        __syncthreads();
    }

    const float mkv = msk[2 + py][2 + pxx];   // mask at output pixel
    #pragma unroll
    for (int oo = 0; oo < 16; ++oo) {
        int o = og * 16 + oo;
        float sc = g2[o] * rsqrtf(v2[o] + EPS);
        float sh = b2[o] - m2[o] * sc;
        float hv = fmaxf(acc[oo] * sc + sh, 0.f) * mkv;
        h2[((size_t)bimg * WIDTH + o) * HW + (ty0 + py) * WW + tx0 + pxx] = hv;
    }
}

// ---------------------------------------------------------------------------
// k3: out = relu(x + bn3(conv3(h2)) * mask)
// GEMM per image: C[64oc x 64px] = W3[64oc x 64] * H2[64 x 64px], 4 oc groups
// ---------------------------------------------------------------------------
__global__ __launch_bounds__(256) void k3_conv3(
    const float* __restrict__ h2, const float* __restrict__ w3,
    const float* __restrict__ g3, const float* __restrict__ b3,
    const float* __restrict__ m3, const float* __restrict__ v3,
    const float* __restrict__ x, const float* __restrict__ mask,
    float* __restrict__ out)
{
    __shared__ float As[32][65];
    __shared__ float Bs[32][65];

    const int tid  = threadIdx.x;
    const int bimg = blockIdx.y;
    const int p0   = blockIdx.x * PXT;
    const int oc0  = blockIdx.z * 64;
    const int tx = tid & 15, ty = tid >> 4;

    float acc[4][4] = {};

    for (int k0 = 0; k0 < WIDTH; k0 += 32) {
        #pragma unroll
        for (int e = 0; e < 8; ++e) {
            int li = tid + 256 * e;
            int m  = li >> 5;
            int kk = li & 31;
            As[kk][m] = w3[(size_t)(oc0 + m) * WIDTH + k0 + kk];
        }
        #pragma unroll
        for (int e = 0; e < 8; ++e) {
            int li = tid + 256 * e;
            int kk = li >> 6;
            int j  = li & 63;
            Bs[kk][j] = h2[((size_t)bimg * WIDTH + k0 + kk) * HW + p0 + j];
        }
        __syncthreads();
        #pragma unroll
        for (int kk = 0; kk < 32; ++kk) {
            float a[4], b[4];
            #pragma unroll
            for (int i = 0; i < 4; ++i) a[i] = As[kk][ty * 4 + i];
            #pragma unroll
            for (int j = 0; j < 4; ++j) b[j] = Bs[kk][tx * 4 + j];
            #pragma unroll
            for (int i = 0; i < 4; ++i)
                #pragma unroll
                for (int j = 0; j < 4; ++j)
                    acc[i][j] += a[i] * b[j];
        }
        __syncthreads();
    }

    float mk[4];
    #pragma unroll
    for (int j = 0; j < 4; ++j) mk[j] = mask[bimg * HW + p0 + tx * 4 + j];

    #pragma unroll
    for (int i = 0; i < 4; ++i) {
        int o = oc0 + ty * 4 + i;
        float sc = g3[o] * rsqrtf(v3[o] + EPS);
        float sh = b3[o] - m3[o] * sc;
        #pragma unroll
        for (int j = 0; j < 4; ++j) {
            size_t idx = ((size_t)bimg * COUT + o) * HW + p0 + tx * 4 + j;
            float hv = (acc[i][j] * sc + sh) * mk[j];
            out[idx] = fmaxf(x[idx] + hv, 0.f);
        }
    }
}

// ---------------------------------------------------------------------------
extern "C" void kernel_launch(void* const* d_in, const int* in_sizes, int n_in,
                              void* d_out, int out_size, void* d_ws, size_t ws_size,
                              hipStream_t stream)
{
    const float* x  = (const float*)d_in[0];
    const float* w1 = (const float*)d_in[1];
    const float* w2 = (const float*)d_in[2];
    const float* w3 = (const float*)d_in[3];
    const float* g1 = (const float*)d_in[4];
    const float* b1 = (const float*)d_in[5];
    const float* m1 = (const float*)d_in[6];
    const float* v1 = (const float*)d_in[7];
    const float* g2 = (const float*)d_in[8];
    const float* b2 = (const float*)d_in[9];
    const float* m2 = (const float*)d_in[10];
    const float* v2 = (const float*)d_in[11];
    const float* g3 = (const float*)d_in[12];
    const float* b3 = (const float*)d_in[13];
    const float* m3 = (const float*)d_in[14];
    const float* v3 = (const float*)d_in[15];
    const float* mw = (const float*)d_in[16];
    const float* mb = (const float*)d_in[17];
    float* outp = (float*)d_out;

    float* h1   = (float*)d_ws;                       // 32*64*3136 floats
    float* h2   = h1 + (size_t)BATCH * WIDTH * HW;    // 32*64*3136 floats
    float* mask = h2 + (size_t)BATCH * WIDTH * HW;    // 32*3136 floats

    dim3 blk(256);
    dim3 g1d(HW / PXT, BATCH);          // 49 x 32
    k1_conv1<<<g1d, blk, 0, stream>>>(x, w1, g1, b1, m1, v1, mw, mb, h1, mask);

    dim3 g2d(WW / 8, HH / 8, BATCH);    // 7 x 7 x 32
    k2_conv2<<<g2d, blk, 0, stream>>>(h1, w2, g2, b2, m2, v2, mask, h2);

    dim3 g3d(HW / PXT, BATCH, COUT / 64); // 49 x 32 x 4
    k3_conv3<<<g3d, blk, 0, stream>>>(h2, w3, g3, b3, m3, v3, x, mask, outp);
}

// Round 2
// 315.140 us; speedup vs baseline: 1.9735x; 1.9735x over previous
//
#include <hip/hip_runtime.h>
#include <hip/hip_bf16.h>

// Sparse bottleneck block, B=32, Cin=Cout=256, width=64, H=W=56. f32 in/out.
// Round 2: k2 (3x3 conv) -> bf16 MFMA implicit GEMM, no LDS in main loop.
// Pipeline: kw (pack w2->bf16 frags) | k1 (conv1+bn1+relu -> h1g bf16 chan-last
// padded, + mask) | k1b (apply dilated mask + zero pad border) | k2_mfma
// (conv2+bn2+relu+*mask -> h2 f32) | k3 (conv3+bn3+*mask+residual+relu).
// ws: h1g bf16 [32][58][58][64] (+4KB slack) | h2 f32 [32][64][3136] |
//     mask f32 [32][3136] | w2p bf16 [9][2][4][64][8]

#define BATCH 32
#define CIN   256
#define WIDTH 64
#define COUT  256
#define HH    56
#define WW    56
#define HW    3136
#define PXT   64
#define EPS   1e-5f

typedef __attribute__((ext_vector_type(8))) short bf16x8;
typedef __attribute__((ext_vector_type(4))) float f32x4;

static __device__ __forceinline__ unsigned short f2bf(float f) {
    __hip_bfloat16 h = __float2bfloat16(f);
    return *reinterpret_cast<unsigned short*>(&h);
}

// ---------------------------------------------------------------------------
// kw: pack w2 [64o][64c][3][3] f32 -> bf16 A-fragments
// layout idx = (((tap*2 + kt)*4 + mt)*64 + l)*8 + j
//   o = mt*16 + (l&15);  c = kt*32 + (l>>4)*8 + j;  tap = dy*3+dx
// ---------------------------------------------------------------------------
__global__ __launch_bounds__(256) void kw_pack(
    const float* __restrict__ w2, __hip_bfloat16* __restrict__ w2p)
{
    int idx = blockIdx.x * 256 + threadIdx.x;
    if (idx >= 9 * 2 * 4 * 64 * 8) return;
    int j   = idx & 7;
    int l   = (idx >> 3) & 63;
    int mt  = (idx >> 9) & 3;
    int kt  = (idx >> 11) & 1;
    int tap = idx >> 12;
    int o = mt * 16 + (l & 15);
    int c = kt * 32 + (l >> 4) * 8 + j;
    unsigned short v = f2bf(w2[(o * WIDTH + c) * 9 + tap]);
    *reinterpret_cast<unsigned short*>(w2p + idx) = v;
}

// ---------------------------------------------------------------------------
// k1: h1g = relu(bn1(conv1(x))) as bf16, channel-last padded [58][58][64];
//     mask[b][p] = (dot(x[b,:,p], mask_w) + mask_b >= 0)
// ---------------------------------------------------------------------------
__global__ __launch_bounds__(256) void k1_conv1(
    const float* __restrict__ x, const float* __restrict__ w1,
    const float* __restrict__ g1, const float* __restrict__ b1,
    const float* __restrict__ m1, const float* __restrict__ v1,
    const float* __restrict__ mw, const float* __restrict__ mb,
    __hip_bfloat16* __restrict__ h1g, float* __restrict__ mask)
{
    __shared__ float As[32][65];
    __shared__ float Bs[32][65];
    __shared__ float mws[32];

    const int tid  = threadIdx.x;
    const int bimg = blockIdx.y;
    const int p0   = blockIdx.x * PXT;
    const float* xb = x + (size_t)bimg * CIN * HW;
    const int tx = tid & 15, ty = tid >> 4;

    float acc[4][4] = {};
    float softacc = 0.f;

    for (int k0 = 0; k0 < CIN; k0 += 32) {
        #pragma unroll
        for (int e = 0; e < 8; ++e) {
            int li = tid + 256 * e;
            int m  = li >> 5;
            int kk = li & 31;
            As[kk][m] = w1[m * CIN + k0 + kk];
        }
        #pragma unroll
        for (int e = 0; e < 8; ++e) {
            int li = tid + 256 * e;
            int kk = li >> 6;
            int j  = li & 63;
            Bs[kk][j] = xb[(size_t)(k0 + kk) * HW + p0 + j];
        }
        if (tid < 32) mws[tid] = mw[k0 + tid];
        __syncthreads();

        #pragma unroll
        for (int kk = 0; kk < 32; ++kk) {
            float a[4], b[4];
            #pragma unroll
            for (int i = 0; i < 4; ++i) a[i] = As[kk][ty * 4 + i];
            #pragma unroll
            for (int j = 0; j < 4; ++j) b[j] = Bs[kk][tx * 4 + j];
            #pragma unroll
            for (int i = 0; i < 4; ++i)
                #pragma unroll
                for (int j = 0; j < 4; ++j)
                    acc[i][j] += a[i] * b[j];
        }
        if (tid < 64) {
            float s = 0.f;
            #pragma unroll
            for (int kk = 0; kk < 32; ++kk) s += Bs[kk][tid] * mws[kk];
            softacc += s;
        }
        __syncthreads();
    }

    float scv[4], shv[4];
    #pragma unroll
    for (int i = 0; i < 4; ++i) {
        int m = ty * 4 + i;
        scv[i] = g1[m] * rsqrtf(v1[m] + EPS);
        shv[i] = b1[m] - m1[m] * scv[i];
    }
    #pragma unroll
    for (int j = 0; j < 4; ++j) {
        int p = p0 + tx * 4 + j;
        int y = p / 56, xc = p - y * 56;
        ushort4 u;
        u.x = f2bf(fmaxf(acc[0][j] * scv[0] + shv[0], 0.f));
        u.y = f2bf(fmaxf(acc[1][j] * scv[1] + shv[1], 0.f));
        u.z = f2bf(fmaxf(acc[2][j] * scv[2] + shv[2], 0.f));
        u.w = f2bf(fmaxf(acc[3][j] * scv[3] + shv[3], 0.f));
        size_t off = (((size_t)bimg * 58 + y + 1) * 58 + xc + 1) * 64 + ty * 4;
        *reinterpret_cast<ushort4*>(h1g + off) = u;
    }
    if (tid < 64) {
        float soft = softacc + mb[0];
        mask[bimg * HW + p0 + tid] = (soft >= 0.f) ? 1.f : 0.f;
    }
}

// ---------------------------------------------------------------------------
// k1b: zero h1g where dilated mask == 0, and zero the 1-px pad border.
// One thread per padded pixel (32*58*58); zeroes its 64-ch (128B) vector.
// ---------------------------------------------------------------------------
__global__ __launch_bounds__(256) void k1b_dilate(
    const float* __restrict__ mask, __hip_bfloat16* __restrict__ h1g)
{
    int idx = blockIdx.x * 256 + threadIdx.x;
    if (idx >= BATCH * 58 * 58) return;
    int b   = idx / 3364;
    int rem = idx - b * 3364;
    int r = rem / 58, c = rem - r * 58;

    bool zero;
    if (r == 0 || r == 57 || c == 0 || c == 57) {
        zero = true;
    } else {
        int y = r - 1, x = c - 1;
        float mx = 0.f;
        #pragma unroll
        for (int dy = -1; dy <= 1; ++dy)
            #pragma unroll
            for (int dx = -1; dx <= 1; ++dx) {
                int yy = y + dy, xx = x + dx;
                if (yy >= 0 && yy < HH && xx >= 0 && xx < WW)
                    mx = fmaxf(mx, mask[b * HW + yy * WW + xx]);
            }
        zero = (mx < 0.5f);
    }
    if (zero) {
        uint4 z = make_uint4(0u, 0u, 0u, 0u);
        uint4* p = reinterpret_cast<uint4*>(h1g + (size_t)idx * 64);
        #pragma unroll
        for (int k = 0; k < 8; ++k) p[k] = z;
    }
}

// ---------------------------------------------------------------------------
// k2: h2 = relu(bn2(conv2(h1g))) * mask, via bf16 MFMA implicit GEMM.
// Block: image b, 2 output rows, all 56 cols, all 64 oc. 4 waves:
//   wave w -> row y0+(w&1), M-half (w>>1). acc = 2 mt x 4 nt frags.
// K = 9 taps x 64 ch -> 18 chunks of 32. A,B frags direct from global.
// ---------------------------------------------------------------------------
__global__ __launch_bounds__(256) void k2_mfma(
    const __hip_bfloat16* __restrict__ h1g,
    const __hip_bfloat16* __restrict__ w2p,
    const float* __restrict__ g2, const float* __restrict__ b2,
    const float* __restrict__ m2, const float* __restrict__ v2,
    const float* __restrict__ mask, float* __restrict__ h2)
{
    const int tid = threadIdx.x;
    const int l = tid & 63, w = tid >> 6;
    const int b = blockIdx.y;
    const int yrow = blockIdx.x * 2 + (w & 1);   // output row 0..55
    const int mh = w >> 1;                        // M-half: oc 32*mh..32*mh+31
    const int ln = l & 15, lg = l >> 4;

    const bf16x8* __restrict__ h1v = reinterpret_cast<const bf16x8*>(h1g)
                                   + (size_t)b * (58 * 58 * 8);
    const bf16x8* __restrict__ w2v = reinterpret_cast<const bf16x8*>(w2p);

    f32x4 acc[2][4];
    #pragma unroll
    for (int i = 0; i < 2; ++i)
        #pragma unroll
        for (int j = 0; j < 4; ++j) acc[i][j] = f32x4{0.f, 0.f, 0.f, 0.f};

    #pragma unroll
    for (int dy = 0; dy < 3; ++dy) {
        const int rr = yrow + dy;                 // padded input row
        #pragma unroll
        for (int dx = 0; dx < 3; ++dx) {
            const int tap = dy * 3 + dx;
            #pragma unroll
            for (int kt = 0; kt < 2; ++kt) {
                bf16x8 a0 = w2v[((tap * 2 + kt) * 4 + mh * 2 + 0) * 64 + l];
                bf16x8 a1 = w2v[((tap * 2 + kt) * 4 + mh * 2 + 1) * 64 + l];
                bf16x8 bf[4];
                #pragma unroll
                for (int nt = 0; nt < 4; ++nt) {
                    int colp = nt * 16 + ln + dx;            // padded col 0..65
                    bf[nt] = h1v[(rr * 58 + colp) * 8 + kt * 4 + lg];
                }
                #pragma unroll
                for (int nt = 0; nt < 4; ++nt) {
                    acc[0][nt] = __builtin_amdgcn_mfma_f32_16x16x32_bf16(
                        a0, bf[nt], acc[0][nt], 0, 0, 0);
                    acc[1][nt] = __builtin_amdgcn_mfma_f32_16x16x32_bf16(
                        a1, bf[nt], acc[1][nt], 0, 0, 0);
                }
            }
        }
    }

    // epilogue: D[o = mt*16 + lg*4 + jj][x = nt*16 + ln]
    float scv[2][4], shv[2][4];
    #pragma unroll
    for (int mi = 0; mi < 2; ++mi)
        #pragma unroll
        for (int jj = 0; jj < 4; ++jj) {
            int o = (mh * 2 + mi) * 16 + lg * 4 + jj;
            float sc = g2[o] * rsqrtf(v2[o] + EPS);
            scv[mi][jj] = sc;
            shv[mi][jj] = b2[o] - m2[o] * sc;
        }
    #pragma unroll
    for (int nt = 0; nt < 4; ++nt) {
        int x = nt * 16 + ln;
        if (x < WW) {
            float mkv = mask[b * HW + yrow * WW + x];
            #pragma unroll
            for (int mi = 0; mi < 2; ++mi)
                #pragma unroll
                for (int jj = 0; jj < 4; ++jj) {
                    int o = (mh * 2 + mi) * 16 + lg * 4 + jj;
                    float hv = fmaxf(acc[mi][nt][jj] * scv[mi][jj] + shv[mi][jj],
                                     0.f) * mkv;
                    h2[((size_t)b * WIDTH + o) * HW + yrow * WW + x] = hv;
                }
        }
    }
}

// ---------------------------------------------------------------------------
// k3: out = relu(x + bn3(conv3(h2)) * mask)  (f32, unchanged)
// ---------------------------------------------------------------------------
__global__ __launch_bounds__(256) void k3_conv3(
    const float* __restrict__ h2, const float* __restrict__ w3,
    const float* __restrict__ g3, const float* __restrict__ b3,
    const float* __restrict__ m3, const float* __restrict__ v3,
    const float* __restrict__ x, const float* __restrict__ mask,
    float* __restrict__ out)
{
    __shared__ float As[32][65];
    __shared__ float Bs[32][65];

    const int tid  = threadIdx.x;
    const int bimg = blockIdx.y;
    const int p0   = blockIdx.x * PXT;
    const int oc0  = blockIdx.z * 64;
    const int tx = tid & 15, ty = tid >> 4;

    float acc[4][4] = {};

    for (int k0 = 0; k0 < WIDTH; k0 += 32) {
        #pragma unroll
        for (int e = 0; e < 8; ++e) {
            int li = tid + 256 * e;
            int m  = li >> 5;
            int kk = li & 31;
            As[kk][m] = w3[(size_t)(oc0 + m) * WIDTH + k0 + kk];
        }
        #pragma unroll
        for (int e = 0; e < 8; ++e) {
            int li = tid + 256 * e;
            int kk = li >> 6;
            int j  = li & 63;
            Bs[kk][j] = h2[((size_t)bimg * WIDTH + k0 + kk) * HW + p0 + j];
        }
        __syncthreads();
        #pragma unroll
        for (int kk = 0; kk < 32; ++kk) {
            float a[4], b[4];
            #pragma unroll
            for (int i = 0; i < 4; ++i) a[i] = As[kk][ty * 4 + i];
            #pragma unroll
            for (int j = 0; j < 4; ++j) b[j] = Bs[kk][tx * 4 + j];
            #pragma unroll
            for (int i = 0; i < 4; ++i)
                #pragma unroll
                for (int j = 0; j < 4; ++j)
                    acc[i][j] += a[i] * b[j];
        }
        __syncthreads();
    }

    float mk[4];
    #pragma unroll
    for (int j = 0; j < 4; ++j) mk[j] = mask[bimg * HW + p0 + tx * 4 + j];

    #pragma unroll
    for (int i = 0; i < 4; ++i) {
        int o = oc0 + ty * 4 + i;
        float sc = g3[o] * rsqrtf(v3[o] + EPS);
        float sh = b3[o] - m3[o] * sc;
        #pragma unroll
        for (int j = 0; j < 4; ++j) {
            size_t idx = ((size_t)bimg * COUT + o) * HW + p0 + tx * 4 + j;
            float hv = (acc[i][j] * sc + sh) * mk[j];
            out[idx] = fmaxf(x[idx] + hv, 0.f);
        }
    }
}

// ---------------------------------------------------------------------------
extern "C" void kernel_launch(void* const* d_in, const int* in_sizes, int n_in,
                              void* d_out, int out_size, void* d_ws, size_t ws_size,
                              hipStream_t stream)
{
    const float* x  = (const float*)d_in[0];
    const float* w1 = (const float*)d_in[1];
    const float* w2 = (const float*)d_in[2];
    const float* w3 = (const float*)d_in[3];
    const float* g1 = (const float*)d_in[4];
    const float* b1 = (const float*)d_in[5];
    const float* m1 = (const float*)d_in[6];
    const float* v1 = (const float*)d_in[7];
    const float* g2 = (const float*)d_in[8];
    const float* b2 = (const float*)d_in[9];
    const float* m2 = (const float*)d_in[10];
    const float* v2 = (const float*)d_in[11];
    const float* g3 = (const float*)d_in[12];
    const float* b3 = (const float*)d_in[13];
    const float* m3 = (const float*)d_in[14];
    const float* v3 = (const float*)d_in[15];
    const float* mw = (const float*)d_in[16];
    const float* mb = (const float*)d_in[17];
    float* outp = (float*)d_out;

    // ws layout
    __hip_bfloat16* h1g = (__hip_bfloat16*)d_ws;            // 32*58*58*64 bf16
    char* p = (char*)d_ws + (size_t)BATCH * 58 * 58 * 64 * 2 + 4096; // slack
    float* h2   = (float*)p;                                // 32*64*3136 f32
    float* mask = h2 + (size_t)BATCH * WIDTH * HW;          // 32*3136 f32
    __hip_bfloat16* w2p = (__hip_bfloat16*)(mask + BATCH * HW); // 36864 bf16

    dim3 blk(256);

    kw_pack<<<dim3(144), blk, 0, stream>>>(w2, w2p);

    dim3 g1d(HW / PXT, BATCH);            // 49 x 32
    k1_conv1<<<g1d, blk, 0, stream>>>(x, w1, g1, b1, m1, v1, mw, mb, h1g, mask);

    int npad = BATCH * 58 * 58;
    k1b_dilate<<<dim3((npad + 255) / 256), blk, 0, stream>>>(mask, h1g);

    dim3 g2d(HH / 2, BATCH);              // 28 x 32
    k2_mfma<<<g2d, blk, 0, stream>>>(h1g, w2p, g2, b2, m2, v2, mask, h2);

    dim3 g3d(HW / PXT, BATCH, COUT / 64); // 49 x 32 x 4
    k3_conv3<<<g3d, blk, 0, stream>>>(h2, w3, g3, b3, m3, v3, x, mask, outp);
}

// Round 3
// 124.603 us; speedup vs baseline: 4.9912x; 2.5291x over previous
//
#include <hip/hip_runtime.h>
#include <hip/hip_bf16.h>

// Sparse bottleneck block, B=32, Cin=Cout=256, width=64, H=W=56. f32 in/out.
// Round 3: ALL three convs as bf16 MFMA implicit GEMM, zero LDS, B-frags
// direct from global (pattern proven by round-2 k2).
// Pipeline: kbn (bn tables) | kw (pack w1/w2/w3 bf16 A-frags) |
//   k1_mfma (conv1+bn1+relu -> h1g bf16 chan-last padded; f32 mask) |
//   k1b (zero h1g where !dilate(mask) + border) |
//   k2_mfma (conv2+bn2+relu+*mask -> h2 bf16 chan-last) |
//   k3_mfma (conv3+bn3+*mask + residual + relu -> out f32)

#define BATCH 32
#define CIN   256
#define WIDTH 64
#define COUT  256
#define HH    56
#define WW    56
#define HW    3136
#define EPS   1e-5f

typedef __attribute__((ext_vector_type(8))) short bf16x8;
typedef __attribute__((ext_vector_type(4))) float f32x4;

static __device__ __forceinline__ unsigned short f2bf(float f) {
    __hip_bfloat16 h = __float2bfloat16(f);
    return *reinterpret_cast<unsigned short*>(&h);
}

// ---------------------------------------------------------------------------
// kbn: bn scale/shift tables.
// tabs: sc1[64] sh1[64] sc2[64] sh2[64] sc3[256] sh3[256]
// ---------------------------------------------------------------------------
__global__ __launch_bounds__(384) void kbn(
    const float* __restrict__ g1, const float* __restrict__ b1,
    const float* __restrict__ m1, const float* __restrict__ v1,
    const float* __restrict__ g2, const float* __restrict__ b2,
    const float* __restrict__ m2, const float* __restrict__ v2,
    const float* __restrict__ g3, const float* __restrict__ b3,
    const float* __restrict__ m3, const float* __restrict__ v3,
    float* __restrict__ tabs)
{
    int t = threadIdx.x;
    if (t < 64) {
        float sc = g1[t] * rsqrtf(v1[t] + EPS);
        tabs[t] = sc; tabs[64 + t] = b1[t] - m1[t] * sc;
    } else if (t < 128) {
        int o = t - 64;
        float sc = g2[o] * rsqrtf(v2[o] + EPS);
        tabs[128 + o] = sc; tabs[192 + o] = b2[o] - m2[o] * sc;
    } else if (t < 384) {
        int o = t - 128;
        float sc = g3[o] * rsqrtf(v3[o] + EPS);
        tabs[256 + o] = sc; tabs[512 + o] = b3[o] - m3[o] * sc;
    }
}

// ---------------------------------------------------------------------------
// kw: pack w1 [64][256], w2 [64][64][3][3], w3 [256][64] into bf16 A-frags.
// Frag layout (all): idx = ((chunk)*NMT + mt)*64*8 + l*8 + j
//   o = mt*16 + (l&15); c = ck*32 + (l>>4)*8 + j
// w1p: 8 kt x 4 mt    (16384) | w2p: (tap*2+kt) x 4 mt (36864)
// w3p: 2 kt x 16 mt   (16384)
// ---------------------------------------------------------------------------
__global__ __launch_bounds__(256) void kw_pack(
    const float* __restrict__ w1, const float* __restrict__ w2,
    const float* __restrict__ w3, __hip_bfloat16* __restrict__ w1p,
    __hip_bfloat16* __restrict__ w2p, __hip_bfloat16* __restrict__ w3p)
{
    int idx = blockIdx.x * 256 + threadIdx.x;
    if (idx < 16384) {                       // w1p
        int j = idx & 7, l = (idx >> 3) & 63;
        int mt = (idx >> 9) & 3, kt = idx >> 11;          // kt 0..7
        int o = mt * 16 + (l & 15);
        int c = kt * 32 + (l >> 4) * 8 + j;
        *reinterpret_cast<unsigned short*>(w1p + idx) = f2bf(w1[o * CIN + c]);
    } else if (idx < 16384 + 36864) {        // w2p
        int i2 = idx - 16384;
        int j = i2 & 7, l = (i2 >> 3) & 63;
        int mt = (i2 >> 9) & 3, kt = (i2 >> 11) & 1, tap = i2 >> 12;
        int o = mt * 16 + (l & 15);
        int c = kt * 32 + (l >> 4) * 8 + j;
        *reinterpret_cast<unsigned short*>(w2p + i2) =
            f2bf(w2[(o * WIDTH + c) * 9 + tap]);
    } else if (idx < 16384 + 36864 + 16384) { // w3p
        int i3 = idx - 16384 - 36864;
        int j = i3 & 7, l = (i3 >> 3) & 63;
        int mt = (i3 >> 9) & 15, kt = i3 >> 13;           // kt 0..1
        int o = mt * 16 + (l & 15);
        int c = kt * 32 + (l >> 4) * 8 + j;
        *reinterpret_cast<unsigned short*>(w3p + i3) = f2bf(w3[o * WIDTH + c]);
    }
}

// ---------------------------------------------------------------------------
// k1: h1g = relu(bn1(conv1(x))) bf16 chan-last padded [58][58][64];
//     mask from f32 dot (computed on pre-conversion f32 values).
// Block = 128 thr = 2 waves; wave does all 64 oc x 32 px, K=256 (8 chunks).
// ---------------------------------------------------------------------------
__global__ __launch_bounds__(128) void k1_mfma(
    const float* __restrict__ x, const __hip_bfloat16* __restrict__ w1p,
    const float* __restrict__ sc1, const float* __restrict__ sh1,
    const float* __restrict__ mw, const float* __restrict__ mb,
    __hip_bfloat16* __restrict__ h1g, float* __restrict__ mask)
{
    const int tid = threadIdx.x;
    const int l = tid & 63, w = tid >> 6;
    const int b = blockIdx.y;
    const int px0 = blockIdx.x * 64 + w * 32;
    const int ln = l & 15, lg = l >> 4;
    const float* __restrict__ xb = x + (size_t)b * CIN * HW;
    const bf16x8* __restrict__ w1v = reinterpret_cast<const bf16x8*>(w1p);

    f32x4 acc[4][2];
    #pragma unroll
    for (int m = 0; m < 4; ++m)
        #pragma unroll
        for (int n = 0; n < 2; ++n) acc[m][n] = f32x4{0.f, 0.f, 0.f, 0.f};

    float msum0 = 0.f, msum1 = 0.f;
    const int p0 = px0 + ln, p1 = px0 + 16 + ln;

    for (int kt = 0; kt < 8; ++kt) {
        const int cb = kt * 32 + lg * 8;
        const float* __restrict__ xc = xb + (size_t)cb * HW;
        float xf0[8], xf1[8];
        #pragma unroll
        for (int j = 0; j < 8; ++j) {
            xf0[j] = xc[(size_t)j * HW + p0];
            xf1[j] = xc[(size_t)j * HW + p1];
        }
        #pragma unroll
        for (int j = 0; j < 8; ++j) {        // f32 mask partial BEFORE cvt
            float mv = mw[cb + j];
            msum0 += xf0[j] * mv;
            msum1 += xf1[j] * mv;
        }
        bf16x8 b0, b1;
        #pragma unroll
        for (int j = 0; j < 8; ++j) {
            b0[j] = (short)f2bf(xf0[j]);
            b1[j] = (short)f2bf(xf1[j]);
        }
        #pragma unroll
        for (int mt = 0; mt < 4; ++mt) {
            bf16x8 a = w1v[(kt * 4 + mt) * 64 + l];
            acc[mt][0] = __builtin_amdgcn_mfma_f32_16x16x32_bf16(a, b0, acc[mt][0], 0, 0, 0);
            acc[mt][1] = __builtin_amdgcn_mfma_f32_16x16x32_bf16(a, b1, acc[mt][1], 0, 0, 0);
        }
    }

    // mask: reduce the 4 lane-groups (k-slices), write from lg==0
    msum0 += __shfl_xor(msum0, 16); msum0 += __shfl_xor(msum0, 32);
    msum1 += __shfl_xor(msum1, 16); msum1 += __shfl_xor(msum1, 32);
    if (lg == 0) {
        float mbv = mb[0];
        mask[b * HW + p0] = (msum0 + mbv >= 0.f) ? 1.f : 0.f;
        mask[b * HW + p1] = (msum1 + mbv >= 0.f) ? 1.f : 0.f;
    }

    // epilogue: D[o = mt*16 + lg*4 + jj][p]
    #pragma unroll
    for (int nt = 0; nt < 2; ++nt) {
        int p = nt ? p1 : p0;
        int y = p / 56, xcn = p - y * 56;
        size_t base = (((size_t)b * 58 + y + 1) * 58 + (xcn + 1)) * 64 + lg * 4;
        #pragma unroll
        for (int mt = 0; mt < 4; ++mt) {
            int ob = mt * 16 + lg * 4;
            ushort4 u;
            u.x = f2bf(fmaxf(acc[mt][nt][0] * sc1[ob + 0] + sh1[ob + 0], 0.f));
            u.y = f2bf(fmaxf(acc[mt][nt][1] * sc1[ob + 1] + sh1[ob + 1], 0.f));
            u.z = f2bf(fmaxf(acc[mt][nt][2] * sc1[ob + 2] + sh1[ob + 2], 0.f));
            u.w = f2bf(fmaxf(acc[mt][nt][3] * sc1[ob + 3] + sh1[ob + 3], 0.f));
            *reinterpret_cast<ushort4*>(h1g + base + mt * 16) = u;
        }
    }
}

// ---------------------------------------------------------------------------
// k1b: zero h1g where dilated mask == 0, and zero the 1-px pad border.
// ---------------------------------------------------------------------------
__global__ __launch_bounds__(256) void k1b_dilate(
    const float* __restrict__ mask, __hip_bfloat16* __restrict__ h1g)
{
    int idx = blockIdx.x * 256 + threadIdx.x;
    if (idx >= BATCH * 58 * 58) return;
    int b   = idx / 3364;
    int rem = idx - b * 3364;
    int r = rem / 58, c = rem - r * 58;

    bool zero;
    if (r == 0 || r == 57 || c == 0 || c == 57) {
        zero = true;
    } else {
        int y = r - 1, x = c - 1;
        float mx = 0.f;
        #pragma unroll
        for (int dy = -1; dy <= 1; ++dy)
            #pragma unroll
            for (int dx = -1; dx <= 1; ++dx) {
                int yy = y + dy, xx = x + dx;
                if (yy >= 0 && yy < HH && xx >= 0 && xx < WW)
                    mx = fmaxf(mx, mask[b * HW + yy * WW + xx]);
            }
        zero = (mx < 0.5f);
    }
    if (zero) {
        uint4 z = make_uint4(0u, 0u, 0u, 0u);
        uint4* p = reinterpret_cast<uint4*>(h1g + (size_t)idx * 64);
        #pragma unroll
        for (int k = 0; k < 8; ++k) p[k] = z;
    }
}

// ---------------------------------------------------------------------------
// k2: h2 = relu(bn2(conv2(h1g))) * mask -> bf16 chan-last [b][p][64].
// Unchanged main loop from round 2 (proven); epilogue now emits bf16.
// ---------------------------------------------------------------------------
__global__ __launch_bounds__(256) void k2_mfma(
    const __hip_bfloat16* __restrict__ h1g,
    const __hip_bfloat16* __restrict__ w2p,
    const float* __restrict__ sc2, const float* __restrict__ sh2,
    const float* __restrict__ mask, __hip_bfloat16* __restrict__ h2)
{
    const int tid = threadIdx.x;
    const int l = tid & 63, w = tid >> 6;
    const int b = blockIdx.y;
    const int yrow = blockIdx.x * 2 + (w & 1);   // output row 0..55
    const int mh = w >> 1;                        // M-half
    const int ln = l & 15, lg = l >> 4;

    const bf16x8* __restrict__ h1v = reinterpret_cast<const bf16x8*>(h1g)
                                   + (size_t)b * (58 * 58 * 8);
    const bf16x8* __restrict__ w2v = reinterpret_cast<const bf16x8*>(w2p);

    f32x4 acc[2][4];
    #pragma unroll
    for (int i = 0; i < 2; ++i)
        #pragma unroll
        for (int j = 0; j < 4; ++j) acc[i][j] = f32x4{0.f, 0.f, 0.f, 0.f};

    #pragma unroll
    for (int dy = 0; dy < 3; ++dy) {
        const int rr = yrow + dy;
        #pragma unroll
        for (int dx = 0; dx < 3; ++dx) {
            const int tap = dy * 3 + dx;
            #pragma unroll
            for (int kt = 0; kt < 2; ++kt) {
                bf16x8 a0 = w2v[((tap * 2 + kt) * 4 + mh * 2 + 0) * 64 + l];
                bf16x8 a1 = w2v[((tap * 2 + kt) * 4 + mh * 2 + 1) * 64 + l];
                bf16x8 bf[4];
                #pragma unroll
                for (int nt = 0; nt < 4; ++nt) {
                    int colp = nt * 16 + ln + dx;
                    bf[nt] = h1v[(rr * 58 + colp) * 8 + kt * 4 + lg];
                }
                #pragma unroll
                for (int nt = 0; nt < 4; ++nt) {
                    acc[0][nt] = __builtin_amdgcn_mfma_f32_16x16x32_bf16(
                        a0, bf[nt], acc[0][nt], 0, 0, 0);
                    acc[1][nt] = __builtin_amdgcn_mfma_f32_16x16x32_bf16(
                        a1, bf[nt], acc[1][nt], 0, 0, 0);
                }
            }
        }
    }

    #pragma unroll
    for (int nt = 0; nt < 4; ++nt) {
        int xc = nt * 16 + ln;
        if (xc < WW) {
            int p = yrow * WW + xc;
            float mkv = mask[b * HW + p];
            #pragma unroll
            for (int mi = 0; mi < 2; ++mi) {
                int ob = (mh * 2 + mi) * 16 + lg * 4;
                ushort4 u;
                u.x = f2bf(fmaxf(acc[mi][nt][0] * sc2[ob + 0] + sh2[ob + 0], 0.f) * mkv);
                u.y = f2bf(fmaxf(acc[mi][nt][1] * sc2[ob + 1] + sh2[ob + 1], 0.f) * mkv);
                u.z = f2bf(fmaxf(acc[mi][nt][2] * sc2[ob + 2] + sh2[ob + 2], 0.f) * mkv);
                u.w = f2bf(fmaxf(acc[mi][nt][3] * sc2[ob + 3] + sh2[ob + 3], 0.f) * mkv);
                *reinterpret_cast<ushort4*>(h2 + ((size_t)b * HW + p) * 64 + ob) = u;
            }
        }
    }
}

// ---------------------------------------------------------------------------
// k3: out = relu(x + bn3(conv3(h2)) * mask). K=64 (2 chunks), B-frags direct
// from h2 bf16 chan-last. Block = 4 waves; wave w -> oc [64w,64w+64), 64 px.
// ---------------------------------------------------------------------------
__global__ __launch_bounds__(256) void k3_mfma(
    const __hip_bfloat16* __restrict__ h2, const __hip_bfloat16* __restrict__ w3p,
    const float* __restrict__ sc3, const float* __restrict__ sh3,
    const float* __restrict__ x, const float* __restrict__ mask,
    float* __restrict__ out)
{
    const int tid = threadIdx.x;
    const int l = tid & 63, w = tid >> 6;
    const int b = blockIdx.y;
    const int px0 = blockIdx.x * 64;
    const int ln = l & 15, lg = l >> 4;

    const bf16x8* __restrict__ h2v = reinterpret_cast<const bf16x8*>(h2)
                                   + (size_t)b * HW * 8;
    const bf16x8* __restrict__ w3v = reinterpret_cast<const bf16x8*>(w3p);

    f32x4 acc[4][4];
    #pragma unroll
    for (int m = 0; m < 4; ++m)
        #pragma unroll
        for (int n = 0; n < 4; ++n) acc[m][n] = f32x4{0.f, 0.f, 0.f, 0.f};

    #pragma unroll
    for (int kt = 0; kt < 2; ++kt) {
        bf16x8 bf[4];
        #pragma unroll
        for (int nt = 0; nt < 4; ++nt)
            bf[nt] = h2v[(size_t)(px0 + nt * 16 + ln) * 8 + kt * 4 + lg];
        #pragma unroll
        for (int m = 0; m < 4; ++m) {
            bf16x8 a = w3v[(kt * 16 + w * 4 + m) * 64 + l];
            #pragma unroll
            for (int nt = 0; nt < 4; ++nt)
                acc[m][nt] = __builtin_amdgcn_mfma_f32_16x16x32_bf16(
                    a, bf[nt], acc[m][nt], 0, 0, 0);
        }
    }

    float mk[4];
    #pragma unroll
    for (int nt = 0; nt < 4; ++nt) mk[nt] = mask[b * HW + px0 + nt * 16 + ln];

    #pragma unroll
    for (int m = 0; m < 4; ++m) {
        #pragma unroll
        for (int jj = 0; jj < 4; ++jj) {
            int o = (w * 4 + m) * 16 + lg * 4 + jj;
            float sc = sc3[o], sh = sh3[o];
            const float* __restrict__ xr = x + ((size_t)b * COUT + o) * HW + px0 + ln;
            float* __restrict__ orow = out + ((size_t)b * COUT + o) * HW + px0 + ln;
            #pragma unroll
            for (int nt = 0; nt < 4; ++nt) {
                float hv = (acc[m][nt][jj] * sc + sh) * mk[nt];
                orow[nt * 16] = fmaxf(xr[nt * 16] + hv, 0.f);
            }
        }
    }
}

// ---------------------------------------------------------------------------
extern "C" void kernel_launch(void* const* d_in, const int* in_sizes, int n_in,
                              void* d_out, int out_size, void* d_ws, size_t ws_size,
                              hipStream_t stream)
{
    const float* x  = (const float*)d_in[0];
    const float* w1 = (const float*)d_in[1];
    const float* w2 = (const float*)d_in[2];
    const float* w3 = (const float*)d_in[3];
    const float* g1 = (const float*)d_in[4];
    const float* b1 = (const float*)d_in[5];
    const float* m1 = (const float*)d_in[6];
    const float* v1 = (const float*)d_in[7];
    const float* g2 = (const float*)d_in[8];
    const float* b2 = (const float*)d_in[9];
    const float* m2 = (const float*)d_in[10];
    const float* v2 = (const float*)d_in[11];
    const float* g3 = (const float*)d_in[12];
    const float* b3 = (const float*)d_in[13];
    const float* m3 = (const float*)d_in[14];
    const float* v3 = (const float*)d_in[15];
    const float* mw = (const float*)d_in[16];
    const float* mb = (const float*)d_in[17];
    float* outp = (float*)d_out;

    // ws layout (all 256B-aligned)
    char* p = (char*)d_ws;
    __hip_bfloat16* h1g = (__hip_bfloat16*)p;  p += (size_t)BATCH * 3364 * 64 * 2;   // 13.8 MB
    __hip_bfloat16* h2  = (__hip_bfloat16*)p;  p += (size_t)BATCH * HW * 64 * 2;     // 12.8 MB
    float* mask = (float*)p;                   p += (size_t)BATCH * HW * 4;          // 0.4 MB
    __hip_bfloat16* w1p = (__hip_bfloat16*)p;  p += 16384 * 2;
    __hip_bfloat16* w2p = (__hip_bfloat16*)p;  p += 36864 * 2;
    __hip_bfloat16* w3p = (__hip_bfloat16*)p;  p += 16384 * 2;
    float* tabs = (float*)p;
    float* sc1 = tabs;       float* sh1 = tabs + 64;
    float* sc2 = tabs + 128; float* sh2 = tabs + 192;
    float* sc3 = tabs + 256; float* sh3 = tabs + 512;

    kbn<<<dim3(1), dim3(384), 0, stream>>>(g1, b1, m1, v1, g2, b2, m2, v2,
                                           g3, b3, m3, v3, tabs);
    kw_pack<<<dim3(272), dim3(256), 0, stream>>>(w1, w2, w3, w1p, w2p, w3p);

    k1_mfma<<<dim3(49, BATCH), dim3(128), 0, stream>>>(x, w1p, sc1, sh1, mw, mb,
                                                       h1g, mask);

    int npad = BATCH * 3364;
    k1b_dilate<<<dim3((npad + 255) / 256), dim3(256), 0, stream>>>(mask, h1g);

    k2_mfma<<<dim3(HH / 2, BATCH), dim3(256), 0, stream>>>(h1g, w2p, sc2, sh2,
                                                           mask, h2);

    k3_mfma<<<dim3(49, BATCH), dim3(256), 0, stream>>>(h2, w3p, sc3, sh3,
                                                       x, mask, outp);
}